// Round 1
// baseline (2807.920 us; speedup 1.0000x reference)
//
// CaptionDecoder on MI355X — round 0: first full implementation.
// Structure: hoist logits GEMM + emb-gate GEMM out of the T=32 serial loop;
// bf16x3 split-precision MFMA for exact-enough GEMMs; f32 recurrence.
#include <hip/hip_runtime.h>

#define E 512
#define H 512
#define V 32000
#define B 32
#define P 196
#define T 32

typedef __attribute__((ext_vector_type(8))) short s8v;    // 8 bf16 (4 VGPRs)
typedef __attribute__((ext_vector_type(4))) float f4v;    // 4 f32 acc

__device__ __forceinline__ float bf16_to_f(unsigned short u){
  return __uint_as_float(((unsigned)u) << 16);
}
__device__ __forceinline__ unsigned short f_to_bf16(float f){
  unsigned u = __float_as_uint(f);
  u += 0x7FFFu + ((u >> 16) & 1u);   // RNE
  return (unsigned short)(u >> 16);
}
__device__ __forceinline__ float fast_tanh(float x){
  float e = __expf(2.0f*x);
  return 1.0f - 2.0f/(e + 1.0f);
}
__device__ __forceinline__ float sigmoidf_(float x){
  return 1.0f/(1.0f + __expf(-x));
}
__device__ __forceinline__ void load_lds16(const unsigned short* g, unsigned short* l){
  __builtin_amdgcn_global_load_lds(
      (const __attribute__((address_space(1))) void*)g,
      (__attribute__((address_space(3))) void*)l, 16, 0, 0);
}

// ---------------------------------------------------------------------------
// Generic split: f32 (strided) -> bf16 hi (+ optional lo residual). cols==512.
__global__ void split_kernel(const float* __restrict__ src, int src_ld, int src_coff,
                             int rows,
                             unsigned short* __restrict__ dhi, unsigned short* __restrict__ dlo,
                             int dst_ld, int dst_coff)
{
  int n = rows << 9;
  for (int i = blockIdx.x*blockDim.x + threadIdx.x; i < n; i += gridDim.x*blockDim.x){
    int r = i >> 9, c = i & 511;
    float x = src[(size_t)r*src_ld + src_coff + c];
    unsigned short h = f_to_bf16(x);
    dhi[(size_t)r*dst_ld + dst_coff + c] = h;
    if (dlo) dlo[(size_t)r*dst_ld + dst_coff + c] = f_to_bf16(x - bf16_to_f(h));
  }
}

// Embedding gather -> bf16 hi/lo, row = b*T+t
__global__ void embed_kernel(const int* __restrict__ caps, const float* __restrict__ embW,
                             unsigned short* __restrict__ ehi, unsigned short* __restrict__ elo)
{
  int row = blockIdx.x;
  int cap = caps[row];
  const float* s = embW + (size_t)cap*E;
  for (int e = threadIdx.x; e < E; e += blockDim.x){
    float x = s[e];
    unsigned short h = f_to_bf16(x);
    ehi[(size_t)row*E + e] = h;
    elo[(size_t)row*E + e] = f_to_bf16(x - bf16_to_f(h));
  }
}

// mean over P, then h0/c0 = mean@W^T + b ; writes f32 state + bf16-split h into x_cat[0]
__global__ __launch_bounds__(512) void prep_kernel(
    const float* __restrict__ feats,
    const float* __restrict__ inith_W, const float* __restrict__ inith_b,
    const float* __restrict__ initc_W, const float* __restrict__ initc_b,
    float* __restrict__ h_state, float* __restrict__ c_state,
    unsigned short* __restrict__ xch, unsigned short* __restrict__ xcl)
{
  __shared__ float mf[E];
  const int b = blockIdx.x, tid = threadIdx.x;
  const float* fb = feats + (size_t)b*P*E + tid;
  float s = 0.f;
  for (int p = 0; p < P; ++p) s += fb[(size_t)p*E];
  mf[tid] = s * (1.0f/196.0f);
  __syncthreads();
  const float* wh = inith_W + (size_t)tid*E;
  const float* wc = initc_W + (size_t)tid*E;
  float h0 = inith_b[tid], c0 = initc_b[tid];
  #pragma unroll 4
  for (int e = 0; e < E; e += 4){
    float4 a4 = *(const float4*)(wh + e);
    float4 b4 = *(const float4*)(wc + e);
    h0 += mf[e]*a4.x + mf[e+1]*a4.y + mf[e+2]*a4.z + mf[e+3]*a4.w;
    c0 += mf[e]*b4.x + mf[e+1]*b4.y + mf[e+2]*b4.z + mf[e+3]*b4.w;
  }
  h_state[b*H + tid] = h0;
  c_state[b*H + tid] = c0;
  unsigned short hh = f_to_bf16(h0);
  xch[b*1024 + 512 + tid] = hh;
  xcl[b*1024 + 512 + tid] = f_to_bf16(h0 - bf16_to_f(hh));
}

// ---------------------------------------------------------------------------
// m97-style bf16 GEMM: C(MxN f32) = sum_passes A_p (MxK) * B_p(NxK)^T [+bias]
// 128x128 tile, BK=32, 4 waves x (64x64), global_load_lds(16B), XOR-swizzled LDS.
__global__ __launch_bounds__(256) void gemm_bt_kernel(
    const unsigned short* __restrict__ A0, const unsigned short* __restrict__ A1,
    const unsigned short* __restrict__ A2,
    const unsigned short* __restrict__ B0, const unsigned short* __restrict__ B1,
    const unsigned short* __restrict__ B2,
    float* __restrict__ Cc, const float* __restrict__ bias,
    int M, int N, int K, int npasses)
{
  __shared__ __align__(16) unsigned short Al[128*32];
  __shared__ __align__(16) unsigned short Bl[128*32];
  const int tid = threadIdx.x;
  const int wid = tid >> 6, l = tid & 63;
  const int m0 = blockIdx.y * 128, n0 = blockIdx.x * 128;
  const int wr = wid >> 1, wc = wid & 1;

  f4v acc[4][4];
  #pragma unroll
  for (int i = 0; i < 4; ++i)
    #pragma unroll
    for (int j = 0; j < 4; ++j) acc[i][j] = (f4v){0.f,0.f,0.f,0.f};

  // staging slots: slot s -> row=s>>2, chunk-slot=s&3; global chunk g = cs ^ ((row>>1)&3)
  const int s0 = tid, s1 = tid + 256;
  const int r0 = s0 >> 2, g0 = (s0 & 3) ^ ((r0 >> 1) & 3);
  const int r1 = s1 >> 2, g1 = (s1 & 3) ^ ((r1 >> 1) & 3);
  const int la = l & 15, ch = l >> 4;

  for (int pass = 0; pass < npasses; ++pass){
    const unsigned short* Ap = pass == 0 ? A0 : (pass == 1 ? A1 : A2);
    const unsigned short* Bp = pass == 0 ? B0 : (pass == 1 ? B1 : B2);
    for (int k0 = 0; k0 < K; k0 += 32){
      __syncthreads();
      load_lds16(Ap + (size_t)(m0 + r0)*K + k0 + g0*8, Al + s0*8);
      load_lds16(Ap + (size_t)(m0 + r1)*K + k0 + g1*8, Al + s1*8);
      load_lds16(Bp + (size_t)(n0 + r0)*K + k0 + g0*8, Bl + s0*8);
      load_lds16(Bp + (size_t)(n0 + r1)*K + k0 + g1*8, Bl + s1*8);
      __syncthreads();
      s8v av[4], bv[4];
      #pragma unroll
      for (int mi = 0; mi < 4; ++mi){
        int row = wr*64 + mi*16 + la;
        int cs = ch ^ ((row >> 1) & 3);
        av[mi] = *(const s8v*)(Al + (row*4 + cs)*8);
      }
      #pragma unroll
      for (int ni = 0; ni < 4; ++ni){
        int row = wc*64 + ni*16 + la;
        int cs = ch ^ ((row >> 1) & 3);
        bv[ni] = *(const s8v*)(Bl + (row*4 + cs)*8);
      }
      #pragma unroll
      for (int mi = 0; mi < 4; ++mi)
        #pragma unroll
        for (int ni = 0; ni < 4; ++ni)
          acc[mi][ni] = __builtin_amdgcn_mfma_f32_16x16x32_bf16(av[mi], bv[ni], acc[mi][ni], 0, 0, 0);
    }
  }
  // epilogue: C/D layout col=lane&15, row=(lane>>4)*4+reg (m89-verified)
  #pragma unroll
  for (int mi = 0; mi < 4; ++mi){
    int row = m0 + wr*64 + mi*16 + (l >> 4)*4;
    #pragma unroll
    for (int ni = 0; ni < 4; ++ni){
      int col = n0 + wc*64 + ni*16 + (l & 15);
      float bb = bias ? bias[col] : 0.0f;
      #pragma unroll
      for (int r = 0; r < 4; ++r)
        Cc[(size_t)(row + r)*N + col] = acc[mi][ni][r] + bb;
    }
  }
}

// ---------------------------------------------------------------------------
// Attention step: one block per batch. hWh -> tanh-energy -> scores -> softmax
// -> context -> bf16-split into x_cat ctx half.
__global__ __launch_bounds__(512) void attn_kernel(
    const float* __restrict__ feat_proj, const float* __restrict__ feats,
    const float* __restrict__ attn_W, const float* __restrict__ attn_b,
    const float* __restrict__ v_w, const float* __restrict__ h_state,
    unsigned short* __restrict__ xch, unsigned short* __restrict__ xcl)
{
  __shared__ float hsm[H];
  __shared__ float hb[H];
  __shared__ float sc[P];
  __shared__ float redv[1];
  const int b = blockIdx.x, tid = threadIdx.x;
  hsm[tid] = h_state[b*H + tid];
  __syncthreads();
  {
    const float* wrow = attn_W + (size_t)tid*(E+H) + E;
    float acc = attn_b[tid];
    #pragma unroll 4
    for (int e = 0; e < H; e += 4){
      float4 w4 = *(const float4*)(wrow + e);
      acc += hsm[e]*w4.x + hsm[e+1]*w4.y + hsm[e+2]*w4.z + hsm[e+3]*w4.w;
    }
    hb[tid] = acc;
  }
  __syncthreads();
  const int l = tid & 63, wv = tid >> 6;
  float hbr[8], vwr[8];
  #pragma unroll
  for (int i = 0; i < 8; ++i){ hbr[i] = hb[l*8 + i]; vwr[i] = v_w[l*8 + i]; }
  const float* fpb = feat_proj + (size_t)b*P*H;
  for (int p = wv; p < P; p += 8){
    const float* fp = fpb + (size_t)p*H + l*8;
    float4 f0 = *(const float4*)fp;
    float4 f1 = *(const float4*)(fp + 4);
    float a = 0.f;
    a += vwr[0]*fast_tanh(f0.x + hbr[0]);
    a += vwr[1]*fast_tanh(f0.y + hbr[1]);
    a += vwr[2]*fast_tanh(f0.z + hbr[2]);
    a += vwr[3]*fast_tanh(f0.w + hbr[3]);
    a += vwr[4]*fast_tanh(f1.x + hbr[4]);
    a += vwr[5]*fast_tanh(f1.y + hbr[5]);
    a += vwr[6]*fast_tanh(f1.z + hbr[6]);
    a += vwr[7]*fast_tanh(f1.w + hbr[7]);
    #pragma unroll
    for (int off = 32; off; off >>= 1) a += __shfl_xor(a, off);
    if (l == 0) sc[p] = a;
  }
  __syncthreads();
  if (tid < 64){
    float m = -1e30f;
    for (int p = tid; p < P; p += 64) m = fmaxf(m, sc[p]);
    #pragma unroll
    for (int off = 32; off; off >>= 1) m = fmaxf(m, __shfl_xor(m, off));
    float s = 0.f;
    for (int p = tid; p < P; p += 64){ float e2 = __expf(sc[p] - m); sc[p] = e2; s += e2; }
    #pragma unroll
    for (int off = 32; off; off >>= 1) s += __shfl_xor(s, off);
    if (tid == 0) redv[0] = 1.0f/s;
  }
  __syncthreads();
  const float inv = redv[0];
  const float* fb = feats + (size_t)b*P*E + tid;
  float a0 = 0.f, a1 = 0.f, a2 = 0.f, a3 = 0.f;
  int p = 0;
  for (; p + 4 <= P; p += 4){
    a0 += sc[p]   * fb[(size_t)p*E];
    a1 += sc[p+1] * fb[(size_t)(p+1)*E];
    a2 += sc[p+2] * fb[(size_t)(p+2)*E];
    a3 += sc[p+3] * fb[(size_t)(p+3)*E];
  }
  for (; p < P; ++p) a0 += sc[p]*fb[(size_t)p*E];
  float ctx = (a0 + a1 + a2 + a3) * inv;
  unsigned short chi = f_to_bf16(ctx);
  xch[b*1024 + tid] = chi;
  xcl[b*1024 + tid] = f_to_bf16(ctx - bf16_to_f(chi));
}

// ---------------------------------------------------------------------------
// LSTM step: gates = x_cat @ Wcat^T (bf16x3, MFMA direct from L2) + gates_emb
// + biases; in-lane i/f/g/o epilogue. 32 blocks (16 j's each), 4 waves K-split.
__global__ __launch_bounds__(256) void lstm_kernel(
    const unsigned short* __restrict__ xrh, const unsigned short* __restrict__ xrl,
    const unsigned short* __restrict__ wch, const unsigned short* __restrict__ wcl,
    const float* __restrict__ gates_emb,
    const float* __restrict__ b_ih, const float* __restrict__ b_hh,
    float* __restrict__ h_state, float* __restrict__ c_state,
    unsigned short* __restrict__ xwh, unsigned short* __restrict__ xwl,
    unsigned short* __restrict__ hall_h, unsigned short* __restrict__ hall_l,
    int t)
{
  __shared__ float red[4][64][33];   // +1 pad: kills 32-way store conflict
  const int tid = threadIdx.x, w = tid >> 6, l = tid & 63;
  const int j0 = blockIdx.x * 16;
  const int la = l & 15;
  const int kk = 8*(l >> 4);
  f4v acc[2][4];
  #pragma unroll
  for (int m = 0; m < 2; ++m)
    #pragma unroll
    for (int g = 0; g < 4; ++g) acc[m][g] = (f4v){0.f,0.f,0.f,0.f};

  #pragma unroll
  for (int pass = 0; pass < 3; ++pass){
    const unsigned short* Aq = (pass == 1) ? xrl : xrh;
    const unsigned short* Bq = (pass == 2) ? wcl : wch;
    const int kbase = w*256 + kk;
    #pragma unroll
    for (int k8 = 0; k8 < 8; ++k8){
      const int k = kbase + k8*32;
      s8v a0 = *(const s8v*)(Aq + (size_t)la*1024 + k);
      s8v a1 = *(const s8v*)(Aq + (size_t)(la + 16)*1024 + k);
      #pragma unroll
      for (int g = 0; g < 4; ++g){
        s8v bv = *(const s8v*)(Bq + (size_t)(g*512 + j0 + la)*1024 + k);
        acc[0][g] = __builtin_amdgcn_mfma_f32_16x16x32_bf16(a0, bv, acc[0][g], 0, 0, 0);
        acc[1][g] = __builtin_amdgcn_mfma_f32_16x16x32_bf16(a1, bv, acc[1][g], 0, 0, 0);
      }
    }
  }
  #pragma unroll
  for (int m = 0; m < 2; ++m)
    #pragma unroll
    for (int g = 0; g < 4; ++g)
      #pragma unroll
      for (int r = 0; r < 4; ++r)
        red[w][l][(m*4+g)*4 + r] = acc[m][g][r];
  __syncthreads();
  for (int q = tid; q < 512; q += 256){
    const int bb = q >> 4;       // batch
    const int jj = q & 15;       // j - j0
    const int m = bb >> 4, lr = bb & 15;
    const int lane = ((lr >> 2) << 4) | jj;
    const int reg = lr & 3;
    float gv[4];
    #pragma unroll
    for (int g = 0; g < 4; ++g){
      const int qq = (m*4+g)*4 + reg;
      float sg = red[0][lane][qq] + red[1][lane][qq] + red[2][lane][qq] + red[3][lane][qq];
      const int col = g*512 + j0 + jj;
      sg += gates_emb[(size_t)(bb*T + t)*2048 + col] + b_ih[col] + b_hh[col];
      gv[g] = sg;
    }
    const float i_ = sigmoidf_(gv[0]);
    const float f_ = sigmoidf_(gv[1]);
    const float g_ = fast_tanh(gv[2]);
    const float o_ = sigmoidf_(gv[3]);
    const int j = j0 + jj;
    const float c_old = c_state[bb*H + j];
    const float c_new = f_*c_old + i_*g_;
    const float h_new = o_*fast_tanh(c_new);
    c_state[bb*H + j] = c_new;
    h_state[bb*H + j] = h_new;
    const unsigned short hh = f_to_bf16(h_new);
    const unsigned short hl = f_to_bf16(h_new - bf16_to_f(hh));
    xwh[bb*1024 + 512 + j] = hh;
    xwl[bb*1024 + 512 + j] = hl;
    hall_h[(size_t)(bb*T + t)*H + j] = hh;
    hall_l[(size_t)(bb*T + t)*H + j] = hl;
  }
}

// ---------------------------------------------------------------------------
extern "C" void kernel_launch(void* const* d_in, const int* in_sizes, int n_in,
                              void* d_out, int out_size, void* d_ws, size_t ws_size,
                              hipStream_t stream)
{
  (void)in_sizes; (void)n_in; (void)out_size;
  const float* features = (const float*)d_in[0];
  const int*   captions = (const int*)d_in[1];
  const float* embed_W  = (const float*)d_in[2];
  const float* attn_W   = (const float*)d_in[3];
  const float* attn_b   = (const float*)d_in[4];
  const float* v_w      = (const float*)d_in[5];
  const float* W_ih     = (const float*)d_in[6];
  const float* W_hh     = (const float*)d_in[7];
  const float* b_ih     = (const float*)d_in[8];
  const float* b_hh     = (const float*)d_in[9];
  const float* lin_W    = (const float*)d_in[10];
  const float* lin_b    = (const float*)d_in[11];
  const float* inith_W  = (const float*)d_in[12];
  const float* inith_b  = (const float*)d_in[13];
  const float* initc_W  = (const float*)d_in[14];
  const float* initc_b  = (const float*)d_in[15];

  // --- "early" scratch lives in d_out (dead before the final logits GEMM writes it)
  char* o = (char*)d_out;
  unsigned short* feat_bf  = (unsigned short*)o; o += (size_t)(B*P)*E*2;   // 6.42MB
  unsigned short* Wf_bf    = (unsigned short*)o; o += (size_t)H*E*2;       // 0.52MB
  float*          feat_proj= (float*)o;          o += (size_t)(B*P)*H*4;   // 12.85MB
  unsigned short* emb_hi   = (unsigned short*)o; o += (size_t)(B*T)*E*2;   // 1.05MB
  unsigned short* emb_lo   = (unsigned short*)o; o += (size_t)(B*T)*E*2;
  float*          gates_emb= (float*)o;          o += (size_t)(B*T)*2048*4;// 8.39MB

  // --- "late" scratch in d_ws
  const size_t SZ_WIH  = (size_t)2048*512*2;
  const size_t SZ_WCAT = (size_t)2048*1024*2;
  const size_t SZ_HALL = (size_t)(B*T)*H*2;
  const size_t SZ_XC   = (size_t)B*1024*2;
  const size_t SZ_ST   = (size_t)B*H*4;
  const size_t SZ_LIN  = (size_t)V*H*2;
  const size_t need_wo_linlo = 2*SZ_WIH + 2*SZ_WCAT + 2*SZ_HALL + 4*SZ_XC + 2*SZ_ST + SZ_LIN;
  const bool three = (ws_size >= need_wo_linlo + SZ_LIN);

  char* w = (char*)d_ws;
  unsigned short* Wih_emb_hi = (unsigned short*)w; w += SZ_WIH;
  unsigned short* Wih_emb_lo = (unsigned short*)w; w += SZ_WIH;
  unsigned short* Wcat_hi    = (unsigned short*)w; w += SZ_WCAT;
  unsigned short* Wcat_lo    = (unsigned short*)w; w += SZ_WCAT;
  unsigned short* hall_hi    = (unsigned short*)w; w += SZ_HALL;
  unsigned short* hall_lo    = (unsigned short*)w; w += SZ_HALL;
  unsigned short* xc_hi0     = (unsigned short*)w; w += SZ_XC;
  unsigned short* xc_lo0     = (unsigned short*)w; w += SZ_XC;
  unsigned short* xc_hi1     = (unsigned short*)w; w += SZ_XC;
  unsigned short* xc_lo1     = (unsigned short*)w; w += SZ_XC;
  float*          h_state    = (float*)w;          w += SZ_ST;
  float*          c_state    = (float*)w;          w += SZ_ST;
  unsigned short* lin_hi     = (unsigned short*)w; w += SZ_LIN;
  unsigned short* lin_lo     = three ? (unsigned short*)w : lin_hi;

  // --- conversions / gathers ---
  split_kernel<<<2048, 256, 0, stream>>>(features, E, 0, B*P, feat_bf, nullptr, E, 0);
  split_kernel<<<256, 256, 0, stream>>>(attn_W, E+H, 0, H, Wf_bf, nullptr, E, 0);
  split_kernel<<<1024, 256, 0, stream>>>(W_ih, 1024, 0, 2048, Wih_emb_hi, Wih_emb_lo, 512, 0);
  split_kernel<<<1024, 256, 0, stream>>>(W_ih, 1024, 512, 2048, Wcat_hi, Wcat_lo, 1024, 0);
  split_kernel<<<1024, 256, 0, stream>>>(W_hh, 512, 0, 2048, Wcat_hi, Wcat_lo, 1024, 512);
  split_kernel<<<2048, 256, 0, stream>>>(lin_W, 512, 0, V, lin_hi, three ? lin_lo : nullptr, 512, 0);
  embed_kernel<<<B*T, 256, 0, stream>>>(captions, embed_W, emb_hi, emb_lo);
  prep_kernel<<<B, 512, 0, stream>>>(features, inith_W, inith_b, initc_W, initc_b,
                                     h_state, c_state, xc_hi0, xc_lo0);

  // --- batched GEMMs (before loop) ---
  // feat_proj = features @ Wf^T  (plain bf16, 1 pass; error damped by softmax)
  gemm_bt_kernel<<<dim3(E/128, (B*P)/128), 256, 0, stream>>>(
      feat_bf, feat_bf, feat_bf, Wf_bf, Wf_bf, Wf_bf,
      feat_proj, nullptr, B*P, E, E, 1);
  // gates_emb = emb @ W_ih[:, :E]^T  (bf16x3)
  gemm_bt_kernel<<<dim3(2048/128, (B*T)/128), 256, 0, stream>>>(
      emb_hi, emb_lo, emb_hi, Wih_emb_hi, Wih_emb_hi, Wih_emb_lo,
      gates_emb, nullptr, B*T, 2048, E, 3);

  // --- sequential decode loop ---
  for (int t = 0; t < T; ++t){
    unsigned short* xrh = (t & 1) ? xc_hi1 : xc_hi0;
    unsigned short* xrl = (t & 1) ? xc_lo1 : xc_lo0;
    unsigned short* xwh = (t & 1) ? xc_hi0 : xc_hi1;
    unsigned short* xwl = (t & 1) ? xc_lo0 : xc_lo1;
    attn_kernel<<<B, 512, 0, stream>>>(feat_proj, features, attn_W, attn_b, v_w,
                                       h_state, xrh, xrl);
    lstm_kernel<<<32, 256, 0, stream>>>(xrh, xrl, Wcat_hi, Wcat_lo, gates_emb,
                                        b_ih, b_hh, h_state, c_state,
                                        xwh, xwl, hall_hi, hall_lo, t);
  }

  // --- logits = h_all @ lin_W^T + lin_b  (bf16x3; overwrites all of d_out) ---
  gemm_bt_kernel<<<dim3(V/128, (B*T)/128), 256, 0, stream>>>(
      hall_hi, hall_lo, hall_hi, lin_hi, lin_hi, lin_lo,
      (float*)d_out, lin_b, B*T, V, H, three ? 3 : 2);
}

// Round 2
// 2463.832 us; speedup vs baseline: 1.1397x; 1.1397x over previous
//
// CaptionDecoder on MI355X — round 2: full-chip per-step phases.
// Loop = 4 slim kernels/step at 256 blocks each, exact-f32 recurrence;
// MFMA (bf16 / bf16x3) only for feat_proj and logits GEMMs.
#include <hip/hip_runtime.h>

#define E 512
#define H 512
#define V 32000
#define B 32
#define P 196
#define T 32

typedef __attribute__((ext_vector_type(8))) short s8v;    // 8 bf16 (4 VGPRs)
typedef __attribute__((ext_vector_type(4))) float f4v;    // 4 f32 acc
typedef unsigned short ushort_t;

__device__ __forceinline__ float bf16_to_f(unsigned short u){
  return __uint_as_float(((unsigned)u) << 16);
}
__device__ __forceinline__ unsigned short f_to_bf16(float f){
  unsigned u = __float_as_uint(f);
  u += 0x7FFFu + ((u >> 16) & 1u);   // RNE
  return (unsigned short)(u >> 16);
}
__device__ __forceinline__ float fast_tanh(float x){
  float e = __expf(2.0f*x);
  return 1.0f - 2.0f/(e + 1.0f);
}
__device__ __forceinline__ float sigmoidf_(float x){
  return 1.0f/(1.0f + __expf(-x));
}
__device__ __forceinline__ void load_lds16(const unsigned short* g, unsigned short* l){
  __builtin_amdgcn_global_load_lds(
      (const __attribute__((address_space(1))) void*)g,
      (__attribute__((address_space(3))) void*)l, 16, 0, 0);
}
__device__ __forceinline__ float dot4(float4 a, float4 b){
  return a.x*b.x + a.y*b.y + a.z*b.z + a.w*b.w;
}

// ---------------------------------------------------------------------------
// f32 (strided) -> bf16 hi (+ optional lo residual). cols==512.
__global__ void split_kernel(const float* __restrict__ src, int src_ld, int src_coff,
                             int rows,
                             unsigned short* __restrict__ dhi, unsigned short* __restrict__ dlo,
                             int dst_ld, int dst_coff)
{
  int n = rows << 9;
  for (int i = blockIdx.x*blockDim.x + threadIdx.x; i < n; i += gridDim.x*blockDim.x){
    int r = i >> 9, c = i & 511;
    float x = src[(size_t)r*src_ld + src_coff + c];
    unsigned short h = f_to_bf16(x);
    dhi[(size_t)r*dst_ld + dst_coff + c] = h;
    if (dlo) dlo[(size_t)r*dst_ld + dst_coff + c] = f_to_bf16(x - bf16_to_f(h));
  }
}

// Embedding gather -> f32, row = b*T+t
__global__ void embed_kernel(const int* __restrict__ caps, const float* __restrict__ embW,
                             float* __restrict__ emb)
{
  int row = blockIdx.x;
  int cap = caps[row];
  const float4* s = (const float4*)(embW + (size_t)cap*E);
  float4* d = (float4*)(emb + (size_t)row*E);
  for (int e = threadIdx.x; e < E/4; e += blockDim.x) d[e] = s[e];
}

// mean over P, then h0/c0 = mean@W^T + b
__global__ __launch_bounds__(512) void prep_kernel(
    const float* __restrict__ feats,
    const float* __restrict__ inith_W, const float* __restrict__ inith_b,
    const float* __restrict__ initc_W, const float* __restrict__ initc_b,
    float* __restrict__ h_state, float* __restrict__ c_state)
{
  __shared__ float mf[E];
  const int b = blockIdx.x, tid = threadIdx.x;
  const float* fb = feats + (size_t)b*P*E + tid;
  float s = 0.f;
  for (int p = 0; p < P; ++p) s += fb[(size_t)p*E];
  mf[tid] = s * (1.0f/196.0f);
  __syncthreads();
  const float* wh = inith_W + (size_t)tid*E;
  const float* wc = initc_W + (size_t)tid*E;
  float h0 = inith_b[tid], c0 = initc_b[tid];
  #pragma unroll 4
  for (int e = 0; e < E; e += 4){
    float4 a4 = *(const float4*)(wh + e);
    float4 b4 = *(const float4*)(wc + e);
    float4 m4 = *(const float4*)(mf + e);
    h0 += dot4(a4, m4);
    c0 += dot4(b4, m4);
  }
  h_state[b*H + tid] = h0;
  c_state[b*H + tid] = c0;
}

// ---------------------------------------------------------------------------
// m97-style bf16 GEMM: C(MxN f32) = sum_passes A_p (MxK) * B_p(NxK)^T [+bias]
// 1-D grid (mt*nt blocks); swz!=0 -> XCD-aware remap (requires grid%8==0).
__global__ __launch_bounds__(256) void gemm_bt_kernel(
    const unsigned short* __restrict__ A0, const unsigned short* __restrict__ A1,
    const unsigned short* __restrict__ A2,
    const unsigned short* __restrict__ B0, const unsigned short* __restrict__ B1,
    const unsigned short* __restrict__ B2,
    float* __restrict__ Cc, const float* __restrict__ bias,
    int N, int K, int npasses, int mt, int swz)
{
  __shared__ __align__(16) unsigned short Al[128*32];
  __shared__ __align__(16) unsigned short Bl[128*32];
  const int tid = threadIdx.x;
  const int wid = tid >> 6, l = tid & 63;
  int f = blockIdx.x;
  if (swz) f = (f & 7)*((int)gridDim.x >> 3) + (f >> 3);
  const int m0 = (f % mt)*128, n0 = (f / mt)*128;
  const int wr = wid >> 1, wc = wid & 1;

  f4v acc[4][4];
  #pragma unroll
  for (int i = 0; i < 4; ++i)
    #pragma unroll
    for (int j = 0; j < 4; ++j) acc[i][j] = (f4v){0.f,0.f,0.f,0.f};

  const int s0 = tid, s1 = tid + 256;
  const int r0 = s0 >> 2, g0 = (s0 & 3) ^ ((r0 >> 1) & 3);
  const int r1 = s1 >> 2, g1 = (s1 & 3) ^ ((r1 >> 1) & 3);
  const int la = l & 15, ch = l >> 4;

  for (int pass = 0; pass < npasses; ++pass){
    const unsigned short* Ap = pass == 0 ? A0 : (pass == 1 ? A1 : A2);
    const unsigned short* Bp = pass == 0 ? B0 : (pass == 1 ? B1 : B2);
    for (int k0 = 0; k0 < K; k0 += 32){
      __syncthreads();
      load_lds16(Ap + (size_t)(m0 + r0)*K + k0 + g0*8, Al + s0*8);
      load_lds16(Ap + (size_t)(m0 + r1)*K + k0 + g1*8, Al + s1*8);
      load_lds16(Bp + (size_t)(n0 + r0)*K + k0 + g0*8, Bl + s0*8);
      load_lds16(Bp + (size_t)(n0 + r1)*K + k0 + g1*8, Bl + s1*8);
      __syncthreads();
      s8v av[4], bv[4];
      #pragma unroll
      for (int mi = 0; mi < 4; ++mi){
        int row = wr*64 + mi*16 + la;
        int cs = ch ^ ((row >> 1) & 3);
        av[mi] = *(const s8v*)(Al + (row*4 + cs)*8);
      }
      #pragma unroll
      for (int ni = 0; ni < 4; ++ni){
        int row = wc*64 + ni*16 + la;
        int cs = ch ^ ((row >> 1) & 3);
        bv[ni] = *(const s8v*)(Bl + (row*4 + cs)*8);
      }
      #pragma unroll
      for (int mi = 0; mi < 4; ++mi)
        #pragma unroll
        for (int ni = 0; ni < 4; ++ni)
          acc[mi][ni] = __builtin_amdgcn_mfma_f32_16x16x32_bf16(av[mi], bv[ni], acc[mi][ni], 0, 0, 0);
    }
  }
  #pragma unroll
  for (int mi = 0; mi < 4; ++mi){
    int row = m0 + wr*64 + mi*16 + (l >> 4)*4;
    #pragma unroll
    for (int ni = 0; ni < 4; ++ni){
      int col = n0 + wc*64 + ni*16 + (l & 15);
      float bb = bias ? bias[col] : 0.0f;
      #pragma unroll
      for (int r = 0; r < 4; ++r)
        Cc[(size_t)(row + r)*N + col] = acc[mi][ni][r] + bb;
    }
  }
}

// ---------------------------------------------------------------------------
// Phase A: hWh[b][j] = h[b]·Wh[j] + attn_b[j].  256 blocks = 32 jc x 8 bc.
__global__ __launch_bounds__(512) void hwh_kernel(
    const float* __restrict__ attn_W, const float* __restrict__ attn_b,
    const float* __restrict__ h_in, float* __restrict__ hWh)
{
  __shared__ float hs[4*520];
  __shared__ float part[64][9];
  const int tid = threadIdx.x;
  const int b0 = (blockIdx.x >> 5)*4, j0 = (blockIdx.x & 31)*16;
  for (int i = tid; i < 2048; i += 512)
    hs[(i >> 9)*520 + (i & 511)] = h_in[(b0 + (i >> 9))*512 + (i & 511)];
  __syncthreads();
  const int o = tid & 63, kt = tid >> 6;
  const int bl = o >> 4, j = j0 + (o & 15);
  const float* wrow = attn_W + (size_t)j*(E+H) + E + kt*64;
  const float* xrow = hs + bl*520 + kt*64;
  float a0 = 0.f, a1 = 0.f;
  #pragma unroll
  for (int i = 0; i < 64; i += 8){
    float4 w0 = *(const float4*)(wrow + i);
    float4 w1 = *(const float4*)(wrow + i + 4);
    float4 x0 = *(const float4*)(xrow + i);
    float4 x1 = *(const float4*)(xrow + i + 4);
    a0 += dot4(w0, x0);
    a1 += dot4(w1, x1);
  }
  part[o][kt] = a0 + a1;
  __syncthreads();
  if (tid < 64){
    float s = attn_b[j0 + (tid & 15)];
    #pragma unroll
    for (int k = 0; k < 8; ++k) s += part[tid][k];
    hWh[(b0 + (tid >> 4))*512 + j0 + (tid & 15)] = s;
  }
}

// Phase B: scores. 256 blocks = 32 b x 8 pc.
__global__ __launch_bounds__(512) void score_kernel(
    const float* __restrict__ feat_proj, const float* __restrict__ hWh,
    const float* __restrict__ v_w, float* __restrict__ sc)
{
  __shared__ float hb[512];
  const int tid = threadIdx.x;
  const int b = blockIdx.x >> 3, pc = blockIdx.x & 7;
  hb[tid] = hWh[b*512 + tid];
  __syncthreads();
  const int l = tid & 63, w = tid >> 6;
  float hbr[8], vwr[8];
  #pragma unroll
  for (int i = 0; i < 8; ++i){ hbr[i] = hb[l*8 + i]; vwr[i] = v_w[l*8 + i]; }
  for (int p = pc + 8*w; p < P; p += 64){
    const float* fp = feat_proj + ((size_t)b*P + p)*512 + l*8;
    float4 f0 = *(const float4*)fp;
    float4 f1 = *(const float4*)(fp + 4);
    float a = 0.f;
    a += vwr[0]*fast_tanh(f0.x + hbr[0]);
    a += vwr[1]*fast_tanh(f0.y + hbr[1]);
    a += vwr[2]*fast_tanh(f0.z + hbr[2]);
    a += vwr[3]*fast_tanh(f0.w + hbr[3]);
    a += vwr[4]*fast_tanh(f1.x + hbr[4]);
    a += vwr[5]*fast_tanh(f1.y + hbr[5]);
    a += vwr[6]*fast_tanh(f1.z + hbr[6]);
    a += vwr[7]*fast_tanh(f1.w + hbr[7]);
    #pragma unroll
    for (int off = 32; off; off >>= 1) a += __shfl_xor(a, off);
    if (l == 0) sc[b*256 + p] = a;
  }
}

// Phase C: softmax + context. 256 blocks = 32 b x 8 ec (64 e each).
__global__ __launch_bounds__(512) void ctx_kernel(
    const float* __restrict__ sc, const float* __restrict__ features,
    float* __restrict__ ctx)
{
  __shared__ float alpha[200];
  __shared__ float inv_s;
  __shared__ float part[8][72];
  const int tid = threadIdx.x;
  const int b = blockIdx.x >> 3, ec = blockIdx.x & 7;
  if (tid < 64){
    const float* sb = sc + b*256;
    float v0 = sb[tid], v1 = sb[tid + 64], v2 = sb[tid + 128];
    float v3 = (tid < 4) ? sb[tid + 192] : -1e30f;
    float m = fmaxf(fmaxf(v0, v1), fmaxf(v2, v3));
    #pragma unroll
    for (int off = 32; off; off >>= 1) m = fmaxf(m, __shfl_xor(m, off));
    float e0 = __expf(v0 - m), e1 = __expf(v1 - m), e2 = __expf(v2 - m);
    float e3 = (tid < 4) ? __expf(v3 - m) : 0.f;
    alpha[tid] = e0; alpha[tid + 64] = e1; alpha[tid + 128] = e2;
    if (tid < 4) alpha[tid + 192] = e3;
    float s = e0 + e1 + e2 + e3;
    #pragma unroll
    for (int off = 32; off; off >>= 1) s += __shfl_xor(s, off);
    if (tid == 0) inv_s = 1.0f/s;
  }
  __syncthreads();
  const int e = ec*64 + (tid & 63), ps = tid >> 6;
  float a = 0.f;
  for (int p = ps; p < P; p += 8)
    a += alpha[p] * features[((size_t)b*P + p)*512 + e];
  part[ps][tid & 63] = a;
  __syncthreads();
  if (tid < 64){
    float s = 0.f;
    #pragma unroll
    for (int k = 0; k < 8; ++k) s += part[k][tid];
    ctx[b*512 + ec*64 + tid] = s * inv_s;
  }
}

// Phase D: gates (exact f32) + LSTM update. 256 blocks = 128 jc x 2 bc.
// Block: 16 b's x 16 cols {g*512 + jc*4 + jj}; 512 thr = 256 outputs x 2 K-halves.
__global__ __launch_bounds__(512) void lstm_kernel(
    const float* __restrict__ emb, const float* __restrict__ ctx,
    const float* __restrict__ h_in,
    const float* __restrict__ W_ih, const float* __restrict__ W_hh,
    const float* __restrict__ b_ih, const float* __restrict__ b_hh,
    float* __restrict__ h_out, float* __restrict__ c_state,
    unsigned short* __restrict__ hall_h, unsigned short* __restrict__ hall_l,
    int t)
{
  __shared__ float xs[16*1540];     // [b][1540]: 0:512 emb | 512:1024 ctx | 1024:1536 h
  __shared__ float part[2][256];
  const int tid = threadIdx.x;
  const int jc = blockIdx.x >> 1, bc = blockIdx.x & 1;
  const int b0 = bc*16;
  for (int i = tid; i < 2048; i += 512){
    int bb = i >> 7, e4 = (i & 127)*4;
    *(float4*)&xs[bb*1540 + e4] = *(const float4*)&emb[((size_t)(b0 + bb)*T + t)*512 + e4];
  }
  for (int i = tid; i < 2048; i += 512){
    int bb = i >> 7, e4 = (i & 127)*4;
    *(float4*)&xs[bb*1540 + 512 + e4] = *(const float4*)&ctx[(b0 + bb)*512 + e4];
  }
  for (int i = tid; i < 2048; i += 512){
    int bb = i >> 7, e4 = (i & 127)*4;
    *(float4*)&xs[bb*1540 + 1024 + e4] = *(const float4*)&h_in[(b0 + bb)*512 + e4];
  }
  __syncthreads();
  const int kh = tid >> 8, q = tid & 255;
  const int bl = q >> 4, ci = q & 15;
  const int col = (ci >> 2)*512 + jc*4 + (ci & 3);
  const float* xrow = xs + bl*1540;
  float a0 = 0.f, a1 = 0.f, a2 = 0.f, a3 = 0.f;
  if (kh == 0){
    const float* wr = W_ih + (size_t)col*1024;
    #pragma unroll 4
    for (int k = 0; k < 768; k += 16){
      float4 w0 = *(const float4*)(wr + k);
      float4 w1 = *(const float4*)(wr + k + 4);
      float4 w2 = *(const float4*)(wr + k + 8);
      float4 w3 = *(const float4*)(wr + k + 12);
      float4 x0 = *(const float4*)(xrow + k);
      float4 x1 = *(const float4*)(xrow + k + 4);
      float4 x2 = *(const float4*)(xrow + k + 8);
      float4 x3 = *(const float4*)(xrow + k + 12);
      a0 += dot4(w0, x0); a1 += dot4(w1, x1);
      a2 += dot4(w2, x2); a3 += dot4(w3, x3);
    }
  } else {
    const float* wr = W_ih + (size_t)col*1024 + 768;
    #pragma unroll 4
    for (int k = 0; k < 256; k += 8){
      float4 w0 = *(const float4*)(wr + k);
      float4 w1 = *(const float4*)(wr + k + 4);
      float4 x0 = *(const float4*)(xrow + 768 + k);
      float4 x1 = *(const float4*)(xrow + 768 + k + 4);
      a0 += dot4(w0, x0); a1 += dot4(w1, x1);
    }
    const float* wr2 = W_hh + (size_t)col*512;
    #pragma unroll 4
    for (int k = 0; k < 512; k += 16){
      float4 w0 = *(const float4*)(wr2 + k);
      float4 w1 = *(const float4*)(wr2 + k + 4);
      float4 w2 = *(const float4*)(wr2 + k + 8);
      float4 w3 = *(const float4*)(wr2 + k + 12);
      float4 x0 = *(const float4*)(xrow + 1024 + k);
      float4 x1 = *(const float4*)(xrow + 1024 + k + 4);
      float4 x2 = *(const float4*)(xrow + 1024 + k + 8);
      float4 x3 = *(const float4*)(xrow + 1024 + k + 12);
      a0 += dot4(w0, x0); a1 += dot4(w1, x1);
      a2 += dot4(w2, x2); a3 += dot4(w3, x3);
    }
  }
  part[kh][q] = (a0 + a1) + (a2 + a3);
  __syncthreads();
  if (tid < 64){
    const int bl2 = tid >> 2, jj = tid & 3;
    const int j = jc*4 + jj;
    float gv[4];
    #pragma unroll
    for (int g = 0; g < 4; ++g){
      const int c2 = g*512 + j;
      const int qq = bl2*16 + g*4 + jj;
      gv[g] = part[0][qq] + part[1][qq] + b_ih[c2] + b_hh[c2];
    }
    const float i_ = sigmoidf_(gv[0]);
    const float f_ = sigmoidf_(gv[1]);
    const float g_ = fast_tanh(gv[2]);
    const float o_ = sigmoidf_(gv[3]);
    const int gb = b0 + bl2;
    const float c_old = c_state[gb*512 + j];
    const float c_new = f_*c_old + i_*g_;
    const float h_new = o_*fast_tanh(c_new);
    c_state[gb*512 + j] = c_new;
    h_out[gb*512 + j] = h_new;
    const unsigned short hh = f_to_bf16(h_new);
    const unsigned short hl = f_to_bf16(h_new - bf16_to_f(hh));
    hall_h[((size_t)gb*T + t)*512 + j] = hh;
    hall_l[((size_t)gb*T + t)*512 + j] = hl;
  }
}

// ---------------------------------------------------------------------------
extern "C" void kernel_launch(void* const* d_in, const int* in_sizes, int n_in,
                              void* d_out, int out_size, void* d_ws, size_t ws_size,
                              hipStream_t stream)
{
  (void)in_sizes; (void)n_in; (void)out_size;
  const float* features = (const float*)d_in[0];
  const int*   captions = (const int*)d_in[1];
  const float* embed_W  = (const float*)d_in[2];
  const float* attn_W   = (const float*)d_in[3];
  const float* attn_b   = (const float*)d_in[4];
  const float* v_w      = (const float*)d_in[5];
  const float* W_ih     = (const float*)d_in[6];
  const float* W_hh     = (const float*)d_in[7];
  const float* b_ih     = (const float*)d_in[8];
  const float* b_hh     = (const float*)d_in[9];
  const float* lin_W    = (const float*)d_in[10];
  const float* lin_b    = (const float*)d_in[11];
  const float* inith_W  = (const float*)d_in[12];
  const float* inith_b  = (const float*)d_in[13];
  const float* initc_W  = (const float*)d_in[14];
  const float* initc_b  = (const float*)d_in[15];

  // "early" scratch in d_out (dead before final logits GEMM writes d_out)
  char* o = (char*)d_out;
  unsigned short* feat_bf   = (unsigned short*)o; o += (size_t)(B*P)*E*2;   // 6.4MB
  unsigned short* Wf_bf     = (unsigned short*)o; o += (size_t)H*E*2;       // 0.5MB
  float*          feat_proj = (float*)o;          o += (size_t)(B*P)*H*4;   // 12.9MB

  // persistent scratch in d_ws
  const size_t SZ_LIN  = (size_t)V*H*2;          // 32.77MB
  const size_t SZ_HALL = (size_t)(B*T)*H*2;      // 1MB
  const size_t SZ_EMB  = (size_t)(B*T)*E*4;      // 2.1MB
  const size_t SZ_ST   = (size_t)B*H*4;          // 64KB
  const size_t SZ_SC   = (size_t)B*256*4;        // 32KB
  const size_t base_need = SZ_LIN + 2*SZ_HALL + SZ_EMB + 4*SZ_ST + SZ_SC + SZ_ST;
  const bool three = (ws_size >= base_need + SZ_LIN);

  char* w = (char*)d_ws;
  unsigned short* lin_hi  = (unsigned short*)w; w += SZ_LIN;
  unsigned short* lin_lo  = (unsigned short*)w; if (three) w += SZ_LIN;
  unsigned short* hall_hi = (unsigned short*)w; w += SZ_HALL;
  unsigned short* hall_lo = (unsigned short*)w; w += SZ_HALL;
  float*          emb_ws  = (float*)w;          w += SZ_EMB;
  float*          hbuf0   = (float*)w;          w += SZ_ST;
  float*          hbuf1   = (float*)w;          w += SZ_ST;
  float*          c_state = (float*)w;          w += SZ_ST;
  float*          hWh_ws  = (float*)w;          w += SZ_ST;
  float*          sc_ws   = (float*)w;          w += SZ_SC;
  float*          ctx_ws  = (float*)w;          w += SZ_ST;

  // --- conversions / gathers / init ---
  split_kernel<<<2048, 256, 0, stream>>>(features, E, 0, B*P, feat_bf, nullptr, E, 0);
  split_kernel<<<256, 256, 0, stream>>>(attn_W, E+H, 0, H, Wf_bf, nullptr, E, 0);
  split_kernel<<<2048, 256, 0, stream>>>(lin_W, 512, 0, V, lin_hi, three ? lin_lo : nullptr, 512, 0);
  embed_kernel<<<B*T, 128, 0, stream>>>(captions, embed_W, emb_ws);
  prep_kernel<<<B, 512, 0, stream>>>(features, inith_W, inith_b, initc_W, initc_b,
                                     hbuf0, c_state);

  // feat_proj = features @ Wf^T  (bf16 1-pass; error damped through tanh/softmax)
  gemm_bt_kernel<<<(B*P/128)*(E/128), 256, 0, stream>>>(
      feat_bf, feat_bf, feat_bf, Wf_bf, Wf_bf, Wf_bf,
      feat_proj, nullptr, E, E, 1, B*P/128, 0);

  // --- sequential decode loop: 4 full-chip phases per step ---
  for (int t = 0; t < T; ++t){
    float* h_in  = (t & 1) ? hbuf1 : hbuf0;
    float* h_out = (t & 1) ? hbuf0 : hbuf1;
    hwh_kernel  <<<256, 512, 0, stream>>>(attn_W, attn_b, h_in, hWh_ws);
    score_kernel<<<256, 512, 0, stream>>>(feat_proj, hWh_ws, v_w, sc_ws);
    ctx_kernel  <<<256, 512, 0, stream>>>(sc_ws, features, ctx_ws);
    lstm_kernel <<<256, 512, 0, stream>>>(emb_ws, ctx_ws, h_in, W_ih, W_hh,
                                          b_ih, b_hh, h_out, c_state,
                                          hall_hi, hall_lo, t);
  }

  // --- logits = h_all @ lin_W^T + lin_b  (bf16x3, XCD-swizzled grid) ---
  gemm_bt_kernel<<<(V/128)*(B*T/128), 256, 0, stream>>>(
      hall_hi, hall_lo, hall_hi, lin_hi, lin_hi, three ? lin_lo : lin_hi,
      (float*)d_out, lin_b, V, H, three ? 3 : 2, B*T/128, 1);
}